// Round 8
// baseline (3112.994 us; speedup 1.0000x reference)
//
#include <hip/hip_runtime.h>
#include <hip/hip_fp16.h>
#include <cstdint>

// mLstm  B=16, P=128, Q=256, D=128, H=128. fp32 in/out (verified R4-R7).
// R8: latency fix. All weight streams are step-invariant -> prefetch into
// registers phases ahead of use (barrier vmcnt drain guarantees arrival).
// tA persistent in regs; Wr LDS-resident; Fh fusion; 4 launches total.

__device__ __forceinline__ float frcp(float x) { return __builtin_amdgcn_rcpf(x); }
__device__ __forceinline__ float2 up2(uint32_t u) {   // fp16 pair -> 2 floats
  __half2 h; __builtin_memcpy(&h, &u, 4); return __half22float2(h);
}
__device__ __forceinline__ uint32_t pk2(float a, float b) {
  __half2 h = __floats2half2_rn(a, b);
  uint32_t u; __builtin_memcpy(&u, &h, 4); return u;
}

// ------------------------------------------------- pack (fp16 uint4 layouts)
//   WrP4[(k8*128+j)*4+c] = pair (Wr[j][k8*8+2c], Wr[j][k8*8+2c+1])   k8<16
//   WgP4[(k8*256+i)*4+c] = pair over Wg[i][k], k<128                 k8<16
//   WT8 [(k8*512+i)*4+c] : k=k8*8+2c; WT[k][i]=k<256?Wih[i][k]:Whh[i][k-256]
//   bb[512]=bih+bhh; wrb/wew/web fp32.
__global__ void pack2(const float* __restrict__ Wr,  const float* __restrict__ Wrb_,
                      const float* __restrict__ Wew_, const float* __restrict__ Web_,
                      const float* __restrict__ Wg,
                      const float* __restrict__ Wih, const float* __restrict__ Whh,
                      const float* __restrict__ bih, const float* __restrict__ bhh,
                      uint32_t* __restrict__ WrP4, float* __restrict__ wrb,
                      float* __restrict__ wew, float* __restrict__ web,
                      uint32_t* __restrict__ WgP4,
                      uint32_t* __restrict__ WT8, float* __restrict__ bb) {
  long idx = (long)blockIdx.x * blockDim.x + threadIdx.x;
  if (idx < 8192) {
    int c = idx & 3, j = (idx >> 2) & 127, k8 = idx >> 9;
    int k = k8 * 8 + 2 * c;
    WrP4[idx] = pk2(Wr[(size_t)j * 128 + k], Wr[(size_t)j * 128 + k + 1]);
    return; }
  idx -= 8192;
  if (idx < 128) { wrb[idx] = Wrb_[idx]; return; }
  idx -= 128;
  if (idx < 128) { wew[idx] = Wew_[idx]; return; }
  idx -= 128;
  if (idx < 1) { web[0] = Web_[0]; return; }
  idx -= 1;
  if (idx < 16384) {
    int c = idx & 3, i = (idx >> 2) & 255, k8 = idx >> 10;
    int k = k8 * 8 + 2 * c;
    WgP4[idx] = pk2(Wg[(size_t)i * 256 + k], Wg[(size_t)i * 256 + k + 1]);
    return; }
  idx -= 16384;
  if (idx < 98304) {
    int c = idx & 3, i = (idx >> 2) & 511, k8 = idx >> 11;
    int k = k8 * 8 + 2 * c;
    float a, b2;
    if (k < 256) { a = Wih[(size_t)i * 256 + k];  b2 = Wih[(size_t)i * 256 + k + 1]; }
    else         { a = Whh[(size_t)i * 128 + (k - 256)];
                   b2 = Whh[(size_t)i * 128 + (k - 255)]; }
    WT8[idx] = pk2(a, b2); return; }
  idx -= 98304;
  if (idx < 512) { bb[idx] = bih[idx] + bhh[idx]; }
}

// ------------------------------------------------------------ fused 3-GEMM
__device__ void gemm_body(const float* __restrict__ A, int lda,
                          const float* __restrict__ W, int ldw, int w_off,
                          const float* __restrict__ bias,
                          float* __restrict__ out, int C, int r0) {
  __shared__ float A_l[16][128];
  __shared__ float W_l[64][129];
  const int t = threadIdx.x;
  for (int idx = t; idx < 16 * 128; idx += 256) {
    int rr = idx >> 7, kk = idx & 127;
    A_l[rr][kk] = A[(size_t)(r0 + rr) * lda + kk];
  }
  const int c_l = t & 63, rg = t >> 6;
  for (int c0 = 0; c0 < C; c0 += 64) {
    __syncthreads();
    for (int idx = t; idx < 64 * 128; idx += 256) {
      int cc = idx >> 7, kk = idx & 127;
      W_l[cc][kk] = W[(size_t)w_off + (size_t)(c0 + cc) * ldw + kk];
    }
    __syncthreads();
    float acc[4] = {0.f, 0.f, 0.f, 0.f};
    for (int k = 0; k < 128; k++) {
      float w = W_l[c_l][k];
#pragma unroll
      for (int x = 0; x < 4; x++) acc[x] = fmaf(A_l[rg * 4 + x][k], w, acc[x]);
    }
    float bv = bias[c0 + c_l];
#pragma unroll
    for (int x = 0; x < 4; x++)
      out[(size_t)(r0 + rg * 4 + x) * C + c0 + c_l] = acc[x] + bv;
  }
}

__global__ __launch_bounds__(256) void gemm3(
    const float* __restrict__ q,  const float* __restrict__ Wsw, const float* __restrict__ Wsb,
    const float* __restrict__ p,  const float* __restrict__ Wtw, const float* __restrict__ Wtb,
    const float* __restrict__ Wgw, const float* __restrict__ Wgb,
    float* __restrict__ whs, float* __restrict__ wht, float* __restrict__ Gp) {
  int blk = blockIdx.x;
  if (blk < 256)      gemm_body(q, 128, Wsw, 128, 0,   Wsb, whs, 128, blk * 16);
  else if (blk < 384) gemm_body(p, 128, Wtw, 128, 0,   Wtb, wht, 128, (blk - 256) * 16);
  else                gemm_body(p, 128, Wgw, 256, 128, Wgb, Gp,  256, (blk - 384) * 16);
}

// From whs (fp32):
//   tA2  [b*16384 + q*64 + h2]         = fp16 pair (tanh over h)
//   whsP4[b*16384 + q8*512 + h*4 + c]  = fp16 pair (whs[q8*8+2c][h], ...+1])
__global__ void tanh_pack(const float* __restrict__ whs,
                          uint32_t* __restrict__ tA2,
                          uint32_t* __restrict__ whsP4) {
  int i = blockIdx.x * blockDim.x + threadIdx.x;  // 0..262143
  {
    int b = i >> 14, qq = (i >> 6) & 255, h2 = i & 63;
    const float* base = whs + (((size_t)b * 256 + qq) << 7) + h2 * 2;
    tA2[i] = pk2(tanhf(base[0]), tanhf(base[1]));
  }
  {
    int b = i >> 14, rem = i & 16383;
    int q8 = rem >> 9, h = (rem >> 2) & 127, c = rem & 3;
    int q = q8 * 8 + 2 * c;
    const float* c0 = whs + (((size_t)b * 256 + q) << 7) + h;
    whsP4[i] = pk2(c0[0], c0[128]);
  }
}

// ---------------------------------------------------------- sequential kernel
__global__ __launch_bounds__(1024, 4) void mlstm_seq6(
    const float* __restrict__ p,         // [16][128][128] fp32
    const uint32_t* __restrict__ tA2g,
    const uint32_t* __restrict__ whsP4g,
    const float* __restrict__ wht_g,     // [16][128][128]
    const float* __restrict__ Gp_g,      // [16][128][256]
    const uint32_t* __restrict__ WrP4,   // [16][128][4]
    const uint32_t* __restrict__ WgP4,   // [16][256][4]
    const uint32_t* __restrict__ WT8,    // [48][512][4]
    const float* __restrict__ bb,
    const float* __restrict__ wrb,
    const float* __restrict__ wew,
    const float* __restrict__ web,
    float* __restrict__ out) {
  const int b = blockIdx.x, t = threadIdx.x;

  __shared__ __align__(16) float part_s[1024];
  __shared__ __align__(16) float partFh_s[1024];
  __shared__ __align__(16) float tu4[440];   // staggered: addr = h + 104*(h>>5)
  __shared__ __align__(16) float we4[440];
  __shared__ __align__(16) float sc_s[256];
  __shared__ __align__(16) float e_s[256];
  __shared__ __align__(16) float xh_s[256];
  __shared__ __align__(16) float alpha_s[128];
  __shared__ __align__(16) float h_s[128];
  __shared__ __align__(16) float c_s[128];
  __shared__ __align__(16) float wrb_s[128];
  __shared__ __align__(16) float bb_s[512];
  __shared__ __align__(16) uint32_t WrL[8192];  // [k2(64)][j(128)], k2 = pair idx
  __shared__ float inv_s, web_s;

  // mappings (wave-uniform group ids; lane-consecutive element ids)
  const int jA = t & 127, kgA = t >> 7;     // A: 8 kgroups x 16 k
  const int qiB = t >> 2, hgB = t & 3;      // B: 256 q x 4 hgroups(32 h)
  const int hD = t & 127, qgD = t >> 7;     // D: 8 qgroups x 32 q
  const int iE = t & 255, kgE = t >> 8;     // E: 4 kgroups x 32 k
  const int iF = t & 511, kgF = t >> 9;     // F/Fh: 2 kgroups

  const uint32_t* tA2b   = tA2g   + ((size_t)b << 14);
  const uint32_t* whsPb  = whsP4g + ((size_t)b << 14);

  // persistent tA fragment (step-invariant)
  uint4 ta_r[4];
#pragma unroll
  for (int jj = 0; jj < 4; jj++)
    ta_r[jj] = *(const uint4*)(tA2b + qiB * 64 + hgB * 16 + jj * 4);

  // LDS init: repack WrP4 -> WrL[k2*128 + j]
  for (int i = t; i < 8192; i += 1024) {
    uint32_t v = WrP4[i];
    int k8 = i >> 9, j = (i >> 2) & 127, c = i & 3;
    WrL[(k8 * 4 + c) * 128 + j] = v;
  }
  if (t < 512) bb_s[t] = bb[t];
  if (t < 128) { wrb_s[t] = wrb[t]; h_s[t] = 0.f; c_s[t] = 0.f;
                 we4[t + 104 * (t >> 5)] = wew[t]; }
  if (t == 0) web_s = web[0];

  // step-0 prefetch: WThh + per-step small vectors
  uint4 whh_r[8];
#pragma unroll
  for (int r = 0; r < 8; r++)
    whh_r[r] = *(const uint4*)(WT8 + ((size_t)(32 + kgF * 8 + r) * 512 + iF) * 4);
  float wht_r = 0.f, gp_r = 0.f, p_r = 0.f;
  if (t < 128) wht_r = wht_g[(size_t)b * 16384 + t];
  if (t < 256) gp_r = Gp_g[(size_t)b * 32768 + t];
  if (t >= 128 && t < 256) p_r = p[(size_t)b * 16384 + (t - 128)];
  __syncthreads();

#pragma unroll 1
  for (int st = 0; st < 128; st++) {
    // ---- A: u-partials (WrL x h) + Fh = Whh x h (whh_r regs)
    {
      float acc = 0.f;
#pragma unroll
      for (int r2 = 0; r2 < 8; r2++) {
        float2 w = up2(WrL[(kgA * 8 + r2) * 128 + jA]);
        acc = fmaf(w.x, h_s[kgA * 16 + r2 * 2], acc);
        acc = fmaf(w.y, h_s[kgA * 16 + r2 * 2 + 1], acc);
      }
      part_s[kgA * 128 + jA] = acc;
    }
    {
      float acc = 0.f;
#pragma unroll
      for (int r = 0; r < 8; r++) {
        uint4 w4 = whh_r[r];
        float2 w0 = up2(w4.x), w1 = up2(w4.y), w2 = up2(w4.z), w3 = up2(w4.w);
        const float* hb = &h_s[(kgF * 8 + r) * 8];
        acc = fmaf(w0.x, hb[0], acc); acc = fmaf(w0.y, hb[1], acc);
        acc = fmaf(w1.x, hb[2], acc); acc = fmaf(w1.y, hb[3], acc);
        acc = fmaf(w2.x, hb[4], acc); acc = fmaf(w2.y, hb[5], acc);
        acc = fmaf(w3.x, hb[6], acc); acc = fmaf(w3.y, hb[7], acc);
      }
      partFh_s[kgF * 512 + iF] = acc;
    }
    __syncthreads();

    // ---- A2: tu (t<128)
    if (t < 128) {
      float u = wrb_s[t] + wht_r;
#pragma unroll
      for (int g = 0; g < 8; g++) u += part_s[g * 128 + t];
      tu4[t + 104 * (t >> 5)] = tanhf(u);
    }
    __syncthreads();

    // ---- B: scores (ta_r regs); issue whs + WTih1 prefetch
    uint4 whs_r[4], wih_r[16];
#pragma unroll
    for (int r = 0; r < 4; r++)
      whs_r[r] = *(const uint4*)(whsPb + (size_t)((qgD * 4 + r) * 512 + hD * 4));
#pragma unroll
    for (int r = 0; r < 8; r++)
      wih_r[r] = *(const uint4*)(WT8 + ((size_t)(kgF * 16 + r) * 512 + iF) * 4);
    {
      const float* tub = tu4 + hgB * 136;
      const float* wee = we4 + hgB * 136;
      float acc = 0.f;
#pragma unroll
      for (int jj = 0; jj < 4; jj++) {
        uint4 a4 = ta_r[jj];
        float2 A0 = up2(a4.x), A1 = up2(a4.y), A2 = up2(a4.z), A3 = up2(a4.w);
        float4 U0 = *(const float4*)(tub + jj * 8);
        float4 U1 = *(const float4*)(tub + jj * 8 + 4);
        float4 W0 = *(const float4*)(wee + jj * 8);
        float4 W1 = *(const float4*)(wee + jj * 8 + 4);
        acc = fmaf((A0.x + U0.x) * frcp(fmaf(A0.x, U0.x, 1.f)), W0.x, acc);
        acc = fmaf((A0.y + U0.y) * frcp(fmaf(A0.y, U0.y, 1.f)), W0.y, acc);
        acc = fmaf((A1.x + U0.z) * frcp(fmaf(A1.x, U0.z, 1.f)), W0.z, acc);
        acc = fmaf((A1.y + U0.w) * frcp(fmaf(A1.y, U0.w, 1.f)), W0.w, acc);
        acc = fmaf((A2.x + U1.x) * frcp(fmaf(A2.x, U1.x, 1.f)), W1.x, acc);
        acc = fmaf((A2.y + U1.y) * frcp(fmaf(A2.y, U1.y, 1.f)), W1.y, acc);
        acc = fmaf((A3.x + U1.z) * frcp(fmaf(A3.x, U1.z, 1.f)), W1.z, acc);
        acc = fmaf((A3.y + U1.w) * frcp(fmaf(A3.y, U1.w, 1.f)), W1.w, acc);
      }
      acc += __shfl_xor(acc, 1);
      acc += __shfl_xor(acc, 2);
      if (hgB == 0) sc_s[qiB] = acc + web_s;
    }
    __syncthreads();

    // ---- C: softmax (wave 0); issue WTih2 prefetch
#pragma unroll
    for (int r = 8; r < 16; r++)
      wih_r[r] = *(const uint4*)(WT8 + ((size_t)(kgF * 16 + r) * 512 + iF) * 4);
    if (t < 64) {
      float s0 = sc_s[t], s1 = sc_s[t + 64], s2 = sc_s[t + 128], s3 = sc_s[t + 192];
      float mx = fmaxf(fmaxf(s0, s1), fmaxf(s2, s3));
#pragma unroll
      for (int d = 1; d < 64; d <<= 1) mx = fmaxf(mx, __shfl_xor(mx, d));
      float e0 = expf(s0 - mx), e1 = expf(s1 - mx),
            e2 = expf(s2 - mx), e3 = expf(s3 - mx);
      float sum = e0 + e1 + e2 + e3;
#pragma unroll
      for (int d = 1; d < 64; d <<= 1) sum += __shfl_xor(sum, d);
      e_s[t] = e0; e_s[t + 64] = e1; e_s[t + 128] = e2; e_s[t + 192] = e3;
      if (t == 0) inv_s = 1.0f / sum;
    }
    __syncthreads();

    // ---- D: alpha partials (whs_r regs)
    {
      float acc = 0.f;
#pragma unroll
      for (int r = 0; r < 4; r++) {
        uint4 w4 = whs_r[r];
        float2 w0 = up2(w4.x), w1 = up2(w4.y), w2 = up2(w4.z), w3 = up2(w4.w);
        int q8 = qgD * 4 + r;
        const float* eb = &e_s[q8 * 8];
        acc = fmaf(w0.x, eb[0], acc); acc = fmaf(w0.y, eb[1], acc);
        acc = fmaf(w1.x, eb[2], acc); acc = fmaf(w1.y, eb[3], acc);
        acc = fmaf(w2.x, eb[4], acc); acc = fmaf(w2.y, eb[5], acc);
        acc = fmaf(w3.x, eb[6], acc); acc = fmaf(w3.y, eb[7], acc);
      }
      part_s[qgD * 128 + hD] = acc;
    }
    __syncthreads();

    // ---- D2: alpha finalize; issue Wg prefetch
    uint4 wg_r[4];
#pragma unroll
    for (int r = 0; r < 4; r++)
      wg_r[r] = *(const uint4*)(WgP4 + (size_t)((kgE * 4 + r) * 256 + iE) * 4);
    if (t < 128) {
      float a = 0.f;
#pragma unroll
      for (int g = 0; g < 8; g++) a += part_s[g * 128 + t];
      alpha_s[t] = a * inv_s;
    }
    __syncthreads();

    // ---- E: gate partials (wg_r regs)
    {
      float acc = 0.f;
#pragma unroll
      for (int r = 0; r < 4; r++) {
        uint4 w4 = wg_r[r];
        float2 w0 = up2(w4.x), w1 = up2(w4.y), w2 = up2(w4.z), w3 = up2(w4.w);
        int k8 = kgE * 4 + r;
        const float* ab = &alpha_s[k8 * 8];
        acc = fmaf(w0.x, ab[0], acc); acc = fmaf(w0.y, ab[1], acc);
        acc = fmaf(w1.x, ab[2], acc); acc = fmaf(w1.y, ab[3], acc);
        acc = fmaf(w2.x, ab[4], acc); acc = fmaf(w2.y, ab[5], acc);
        acc = fmaf(w3.x, ab[6], acc); acc = fmaf(w3.y, ab[7], acc);
      }
      part_s[kgE * 256 + iE] = acc;
    }
    __syncthreads();

    // ---- E2: xh (t<256)
    if (t < 256) {
      float g = gp_r;
#pragma unroll
      for (int gg = 0; gg < 4; gg++) g += part_s[gg * 256 + t];
      float sg = 1.0f / (1.0f + expf(-g));
      float xv = (t < 128) ? alpha_s[t] : p_r;
      xh_s[t] = sg * xv;
    }
    __syncthreads();

    // ---- F: Wih x xh partials (wih_r regs)
    {
      float acc = 0.f;
#pragma unroll
      for (int r = 0; r < 16; r++) {
        uint4 w4 = wih_r[r];
        float2 w0 = up2(w4.x), w1 = up2(w4.y), w2 = up2(w4.z), w3 = up2(w4.w);
        const float* xb = &xh_s[(kgF * 16 + r) * 8];
        acc = fmaf(w0.x, xb[0], acc); acc = fmaf(w0.y, xb[1], acc);
        acc = fmaf(w1.x, xb[2], acc); acc = fmaf(w1.y, xb[3], acc);
        acc = fmaf(w2.x, xb[4], acc); acc = fmaf(w2.y, xb[5], acc);
        acc = fmaf(w3.x, xb[6], acc); acc = fmaf(w3.y, xb[7], acc);
      }
      part_s[kgF * 512 + iF] = acc;
    }
    __syncthreads();

    // ---- G: gate sums + LSTM cell; prefetch next step's WThh + small vecs
    if (t < 128) {
      float g0 = part_s[t]       + part_s[512 + t] + partFh_s[t]       + partFh_s[512 + t] + bb_s[t];
      float g1 = part_s[128 + t] + part_s[640 + t] + partFh_s[128 + t] + partFh_s[640 + t] + bb_s[128 + t];
      float g2 = part_s[256 + t] + part_s[768 + t] + partFh_s[256 + t] + partFh_s[768 + t] + bb_s[256 + t];
      float g3 = part_s[384 + t] + part_s[896 + t] + partFh_s[384 + t] + partFh_s[896 + t] + bb_s[384 + t];
      float iv = 1.0f / (1.0f + expf(-g0));
      float fv = 1.0f / (1.0f + expf(-g1));
      float gv = tanhf(g2);
      float ov = 1.0f / (1.0f + expf(-g3));
      float cn = fmaf(fv, c_s[t], iv * gv);
      float hn = ov * tanhf(cn);
      c_s[t] = cn; h_s[t] = hn;
      out[((size_t)b * 128 + st) * 128 + t] = hn;
    }
    int sn = (st + 1 < 128) ? st + 1 : st;
#pragma unroll
    for (int r = 0; r < 8; r++)
      whh_r[r] = *(const uint4*)(WT8 + ((size_t)(32 + kgF * 8 + r) * 512 + iF) * 4);
    if (t < 128) wht_r = wht_g[((size_t)b * 128 + sn) * 128 + t];
    if (t < 256) gp_r = Gp_g[((size_t)b * 128 + sn) * 256 + t];
    if (t >= 128 && t < 256) p_r = p[((size_t)b * 128 + sn) * 128 + (t - 128)];
    __syncthreads();
  }
}

// ----------------------------------------------------------------- launcher
extern "C" void kernel_launch(void* const* d_in, const int* in_sizes, int n_in,
                              void* d_out, int out_size, void* d_ws, size_t ws_size,
                              hipStream_t stream) {
  static const int SZ_DICT[18] = {262144, 524288, 16384, 128, 16384, 128,
                                  16384, 128, 128, 1, 65536, 256,
                                  131072, 65536, 512, 512, 2048, 4096};
  static const int ALPHA2DICT[18] = {9, 8, 11, 10, 13, 12, 7, 6, 3, 2, 5, 4,
                                     15, 14, 0, 16, 1, 17};
  const void* in[18];
  for (int i = 0; i < 18; i++) in[i] = (i < n_in) ? d_in[i] : nullptr;
  bool dict_ok = true;
  int lim = (n_in < 16) ? n_in : 16;
  for (int i = 0; i < lim; i++) if (in_sizes[i] != SZ_DICT[i]) dict_ok = false;
  if (!dict_ok) {
    bool alpha_ok = true;
    for (int s = 0; s < n_in && s < 18; s++)
      if (in_sizes[s] != SZ_DICT[ALPHA2DICT[s]]) alpha_ok = false;
    if (alpha_ok)
      for (int s = 0; s < n_in && s < 18; s++) in[ALPHA2DICT[s]] = d_in[s];
  }

  const float* p   = (const float*)in[0];  const float* q   = (const float*)in[1];
  const float* Wsw = (const float*)in[2];  const float* Wsb = (const float*)in[3];
  const float* Wtw = (const float*)in[4];  const float* Wtb = (const float*)in[5];
  const float* Wrw = (const float*)in[6];  const float* Wrb = (const float*)in[7];
  const float* Wew = (const float*)in[8];  const float* Web = (const float*)in[9];
  const float* Wgw = (const float*)in[10]; const float* Wgb = (const float*)in[11];
  const float* Wih = (const float*)in[12]; const float* Whh = (const float*)in[13];
  const float* bih = (const float*)in[14]; const float* bhh = (const float*)in[15];

  float* ws = (float*)d_ws;
  float*    whs   = ws;                          // 524288 f
  uint32_t* tA2   = (uint32_t*)(whs + 524288);   // 262144 u32
  uint32_t* whsP4 = tA2 + 262144;                // 262144 u32
  float*    wht   = (float*)(whsP4 + 262144);    // 262144 f
  float*    Gp    = wht + 262144;                // 524288 f
  uint32_t* WrP4  = (uint32_t*)(Gp + 524288);    // 8192 u32
  uint32_t* WgP4  = WrP4 + 8192;                 // 16384 u32
  uint32_t* WT8   = WgP4 + 16384;                // 98304 u32
  float*    bb    = (float*)(WT8 + 98304);       // 512 f
  float*    wrb   = bb + 512;                    // 128
  float*    wew   = wrb + 128;                   // 128
  float*    web   = wew + 128;                   // 4 (1 used)  ~8.4 MB total

  hipLaunchKernelGGL(pack2, dim3(484), dim3(256), 0, stream,
                     Wrw, Wrb, Wew, Web, Wgw, Wih, Whh, bih, bhh,
                     WrP4, wrb, wew, web, WgP4, WT8, bb);
  hipLaunchKernelGGL(gemm3, dim3(512), dim3(256), 0, stream,
                     q, Wsw, Wsb, p, Wtw, Wtb, Wgw, Wgb, whs, wht, Gp);
  hipLaunchKernelGGL(tanh_pack, dim3(1024), dim3(256), 0, stream,
                     whs, tA2, whsP4);
  hipLaunchKernelGGL(mlstm_seq6, dim3(16), dim3(1024), 0, stream,
                     p, tA2, whsP4, wht, Gp, WrP4, WgP4, WT8, bb, wrb, wew,
                     web, (float*)d_out);
}